// Round 1
// baseline (99.459 us; speedup 1.0000x reference)
//
#include <hip/hip_runtime.h>
#include <hip/hip_bf16.h>

#define NB 8
#define SEQ 2048
#define DIN 1024
#define DH 64

typedef __attribute__((ext_vector_type(8))) short bf16x8;
typedef __attribute__((ext_vector_type(4))) float f32x4;

static __device__ __forceinline__ unsigned short f2bf(float f) {
    unsigned int u = __builtin_bit_cast(unsigned int, f);
    unsigned int r = (u + 0x7FFFu + ((u >> 16) & 1u)) >> 16;
    return (unsigned short)r;
}

// ---------------- prep: Wt[mat][col][k] = bf16(W[k][col]);  bias = mask ? -1e30 : 0
__global__ __launch_bounds__(256) void prep_kernel(
    const float* __restrict__ Wq, const float* __restrict__ Wk, const float* __restrict__ Wv,
    const int* __restrict__ mask, unsigned short* __restrict__ Wt, float* __restrict__ bias)
{
    int i = blockIdx.x * 256 + threadIdx.x;
    if (i < 3 * DH * DIN) {
        int mat = i >> 16;            // DH*DIN = 65536
        int c   = (i >> 10) & 63;
        int k   = i & 1023;
        const float* W = (mat == 0) ? Wq : ((mat == 1) ? Wk : Wv);
        Wt[i] = f2bf(W[k * DH + c]);
    } else {
        int j = i - 3 * DH * DIN;
        if (j < NB * SEQ) bias[j] = mask[j] ? -1e30f : 0.0f;
    }
}

// ---------------- QKV GEMM: X[16384x1024] fp32 -> Qb,Kb [16384x64] bf16, Vt [8][64][2048] bf16
#define BM 32
#define BK 64
#define APAD 88  // shorts per LDS row (176B: 16B aligned, 2-way-free banks)

__global__ __launch_bounds__(256) void qkv_kernel(
    const float* __restrict__ X, const unsigned short* __restrict__ Wt,
    const float* __restrict__ bq, const float* __restrict__ bk, const float* __restrict__ bv,
    unsigned short* __restrict__ Qb, unsigned short* __restrict__ Kb, unsigned short* __restrict__ Vt)
{
    __shared__ short As[BM][APAD];

    const int tid = threadIdx.x;
    const int w   = tid >> 6;       // wave 0..3 -> 48-col stripe
    const int l   = tid & 63;
    const int l15 = l & 15;
    const int lq  = l >> 4;
    const int row0 = blockIdx.x * BM;

    f32x4 acc[2][3] = {};

    const int srow = tid >> 3;           // staging: 8 floats/thread
    const int sk   = (tid & 7) * 8;
    const float* xbase = X + (size_t)(row0 + srow) * DIN + sk;

    for (int step = 0; step < DIN / BK; ++step) {
        float4 v0 = *(const float4*)(xbase + step * BK);
        float4 v1 = *(const float4*)(xbase + step * BK + 4);
        bf16x8 sv;
        sv[0] = (short)f2bf(v0.x); sv[1] = (short)f2bf(v0.y);
        sv[2] = (short)f2bf(v0.z); sv[3] = (short)f2bf(v0.w);
        sv[4] = (short)f2bf(v1.x); sv[5] = (short)f2bf(v1.y);
        sv[6] = (short)f2bf(v1.z); sv[7] = (short)f2bf(v1.w);

        // B frags straight from L2-resident Wt (no barrier needed)
        bf16x8 bfr[3][2];
        #pragma unroll
        for (int n = 0; n < 3; ++n) {
            int col = w * 48 + n * 16 + l15;
            int mat = col >> 6, c = col & 63;
            const unsigned short* wp = Wt + ((size_t)(mat * DH + c)) * DIN + step * BK + lq * 8;
            bfr[n][0] = *(const bf16x8*)(wp);
            bfr[n][1] = *(const bf16x8*)(wp + 32);
        }

        __syncthreads();
        *(bf16x8*)&As[srow][sk] = sv;
        __syncthreads();

        bf16x8 a[2][2];
        #pragma unroll
        for (int m = 0; m < 2; ++m)
            #pragma unroll
            for (int kk = 0; kk < 2; ++kk)
                a[m][kk] = *(const bf16x8*)&As[m * 16 + l15][kk * 32 + lq * 8];

        #pragma unroll
        for (int kk = 0; kk < 2; ++kk)
            #pragma unroll
            for (int m = 0; m < 2; ++m)
                #pragma unroll
                for (int n = 0; n < 3; ++n)
                    acc[m][n] = __builtin_amdgcn_mfma_f32_16x16x32_bf16(a[m][kk], bfr[n][kk], acc[m][n], 0, 0, 0);
    }

    // epilogue
    #pragma unroll
    for (int n = 0; n < 3; ++n) {
        int col = w * 48 + n * 16 + l15;
        int mat = col >> 6, c = col & 63;
        float badd = ((mat == 0) ? bq : ((mat == 1) ? bk : bv))[c];
        #pragma unroll
        for (int m = 0; m < 2; ++m) {
            #pragma unroll
            for (int reg = 0; reg < 4; ++reg) {
                int row = row0 + m * 16 + lq * 4 + reg;
                unsigned short v16 = f2bf(acc[m][n][reg] + badd);
                if (mat == 0)      Qb[(size_t)row * DH + c] = v16;
                else if (mat == 1) Kb[(size_t)row * DH + c] = v16;
                else {
                    int bb = row >> 11, ss = row & 2047;
                    Vt[((size_t)(bb * DH + c)) * SEQ + ss] = v16;
                }
            }
        }
    }
}

// ---------------- flash attention: block = (batch, 16 q-rows); 4 waves split 2048 keys
#define PPAD 88   // shorts
#define OPAD 68   // floats

__global__ __launch_bounds__(256) void attn_kernel(
    const unsigned short* __restrict__ Qb, const unsigned short* __restrict__ Kb,
    const unsigned short* __restrict__ Vt, const float* __restrict__ bias,
    float* __restrict__ out)
{
    __shared__ short Ps[4][16][PPAD];
    __shared__ float smO[4][16][OPAD];
    __shared__ float smm[4][16];
    __shared__ float sml[4][16];

    const int tid = threadIdx.x;
    const int w   = tid >> 6;
    const int l   = tid & 63;
    const int l15 = l & 15;
    const int lq  = l >> 4;
    const int b   = blockIdx.x >> 7;
    const int q0  = (blockIdx.x & 127) * 16;

    // persistent Q fragments
    const unsigned short* qp = Qb + ((size_t)(b * SEQ + q0 + l15)) * DH + lq * 8;
    bf16x8 aq[2];
    aq[0] = *(const bf16x8*)qp;
    aq[1] = *(const bf16x8*)(qp + 32);

    f32x4 mrow, lrow, o[4];
    #pragma unroll
    for (int r = 0; r < 4; ++r) { mrow[r] = -1e30f; lrow[r] = 0.0f; }
    o[0] = f32x4{0,0,0,0}; o[1] = o[0]; o[2] = o[0]; o[3] = o[0];

    const float rscale = 0.022097086912079612f;  // 1/sqrt(2048)

    for (int kt = 0; kt < 8; ++kt) {
        const int key0 = w * 512 + kt * 64;

        // K fragments
        bf16x8 bk8[4][2];
        const unsigned short* kp = Kb + ((size_t)(b * SEQ + key0 + l15)) * DH + lq * 8;
        #pragma unroll
        for (int n = 0; n < 4; ++n) {
            bk8[n][0] = *(const bf16x8*)(kp + (size_t)n * 16 * DH);
            bk8[n][1] = *(const bf16x8*)(kp + (size_t)n * 16 * DH + 32);
        }

        f32x4 s[4] = {};
        #pragma unroll
        for (int kk = 0; kk < 2; ++kk)
            #pragma unroll
            for (int n = 0; n < 4; ++n)
                s[n] = __builtin_amdgcn_mfma_f32_16x16x32_bf16(aq[kk], bk8[n][kk], s[n], 0, 0, 0);

        // scale + mask bias (per key column)
        #pragma unroll
        for (int n = 0; n < 4; ++n) {
            float bvv = bias[b * SEQ + key0 + n * 16 + l15];
            #pragma unroll
            for (int r = 0; r < 4; ++r) s[n][r] = s[n][r] * rscale + bvv;
        }

        // row max over 4 frags + 16 lanes
        f32x4 tm;
        #pragma unroll
        for (int r = 0; r < 4; ++r)
            tm[r] = fmaxf(fmaxf(s[0][r], s[1][r]), fmaxf(s[2][r], s[3][r]));
        #pragma unroll
        for (int off = 1; off < 16; off <<= 1)
            #pragma unroll
            for (int r = 0; r < 4; ++r) tm[r] = fmaxf(tm[r], __shfl_xor(tm[r], off));

        f32x4 fac;
        #pragma unroll
        for (int r = 0; r < 4; ++r) {
            float mn = fmaxf(mrow[r], tm[r]);
            fac[r] = __expf(mrow[r] - mn);
            mrow[r] = mn;
        }
        #pragma unroll
        for (int n = 0; n < 4; ++n)
            #pragma unroll
            for (int r = 0; r < 4; ++r) o[n][r] *= fac[r];

        f32x4 p[4], psum = {};
        #pragma unroll
        for (int n = 0; n < 4; ++n)
            #pragma unroll
            for (int r = 0; r < 4; ++r) { p[n][r] = __expf(s[n][r] - mrow[r]); psum[r] += p[n][r]; }
        #pragma unroll
        for (int off = 1; off < 16; off <<= 1)
            #pragma unroll
            for (int r = 0; r < 4; ++r) psum[r] += __shfl_xor(psum[r], off);
        #pragma unroll
        for (int r = 0; r < 4; ++r) lrow[r] = lrow[r] * fac[r] + psum[r];

        // P -> LDS (re-layout for PV A-fragment)
        #pragma unroll
        for (int n = 0; n < 4; ++n)
            #pragma unroll
            for (int r = 0; r < 4; ++r)
                Ps[w][lq * 4 + r][n * 16 + l15] = (short)f2bf(p[n][r]);

        bf16x8 pa[2];
        pa[0] = *(const bf16x8*)&Ps[w][l15][lq * 8];
        pa[1] = *(const bf16x8*)&Ps[w][l15][32 + lq * 8];

        // V fragments (from transposed Vt: contiguous)
        bf16x8 bv8[4][2];
        const unsigned short* vp = Vt + ((size_t)(b * DH + l15)) * SEQ + key0 + lq * 8;
        #pragma unroll
        for (int n = 0; n < 4; ++n) {
            bv8[n][0] = *(const bf16x8*)(vp + (size_t)n * 16 * SEQ);
            bv8[n][1] = *(const bf16x8*)(vp + (size_t)n * 16 * SEQ + 32);
        }
        #pragma unroll
        for (int kk = 0; kk < 2; ++kk)
            #pragma unroll
            for (int n = 0; n < 4; ++n)
                o[n] = __builtin_amdgcn_mfma_f32_16x16x32_bf16(pa[kk], bv8[n][kk], o[n], 0, 0, 0);
    }

    // -------- combine 4 waves (same 16 q-rows, disjoint keys)
    if (l15 == 0) {
        #pragma unroll
        for (int r = 0; r < 4; ++r) { smm[w][lq * 4 + r] = mrow[r]; sml[w][lq * 4 + r] = lrow[r]; }
    }
    __syncthreads();

    f32x4 scl;
    #pragma unroll
    for (int r = 0; r < 4; ++r) {
        int q = lq * 4 + r;
        float mm = fmaxf(fmaxf(smm[0][q], smm[1][q]), fmaxf(smm[2][q], smm[3][q]));
        scl[r] = __expf(mrow[r] - mm);
    }
    #pragma unroll
    for (int n = 0; n < 4; ++n)
        #pragma unroll
        for (int r = 0; r < 4; ++r)
            smO[w][lq * 4 + r][n * 16 + l15] = o[n][r] * scl[r];
    __syncthreads();

    // final: each thread writes one float4 of the 16x64 output tile
    {
        int q  = tid >> 4;
        int d0 = (tid & 15) * 4;
        float mm = fmaxf(fmaxf(smm[0][q], smm[1][q]), fmaxf(smm[2][q], smm[3][q]));
        float lst = 0.0f;
        #pragma unroll
        for (int wv = 0; wv < 4; ++wv) lst += sml[wv][q] * __expf(smm[wv][q] - mm);
        float inv = 1.0f / lst;
        float4 r4;
        float vx[4];
        #pragma unroll
        for (int i = 0; i < 4; ++i)
            vx[i] = (smO[0][q][d0 + i] + smO[1][q][d0 + i] + smO[2][q][d0 + i] + smO[3][q][d0 + i]) * inv;
        r4.x = vx[0]; r4.y = vx[1]; r4.z = vx[2]; r4.w = vx[3];
        *(float4*)(out + ((size_t)(b * SEQ + q0 + q)) * DH + d0) = r4;
    }
}

extern "C" void kernel_launch(void* const* d_in, const int* in_sizes, int n_in,
                              void* d_out, int out_size, void* d_ws, size_t ws_size,
                              hipStream_t stream) {
    const float* X    = (const float*)d_in[0];
    const int*   mask = (const int*)d_in[1];
    const float* Wq   = (const float*)d_in[2];
    const float* bq   = (const float*)d_in[3];
    const float* Wk   = (const float*)d_in[4];
    const float* bk   = (const float*)d_in[5];
    const float* Wv   = (const float*)d_in[6];
    const float* bv   = (const float*)d_in[7];
    float* out = (float*)d_out;

    char* ws = (char*)d_ws;
    unsigned short* Qb = (unsigned short*)(ws);                       // 2 MiB
    unsigned short* Kb = (unsigned short*)(ws + (2u << 20));          // 2 MiB
    unsigned short* Vt = (unsigned short*)(ws + (4u << 20));          // 2 MiB
    unsigned short* Wt = (unsigned short*)(ws + (6u << 20));          // 384 KiB
    float* bias        = (float*)(ws + (6u << 20) + 3 * DH * DIN * 2); // 64 KiB

    prep_kernel<<<832, 256, 0, stream>>>(Wq, Wk, Wv, mask, Wt, bias);
    qkv_kernel<<<512, 256, 0, stream>>>(X, Wt, bq, bk, bv, Qb, Kb, Vt);
    attn_kernel<<<1024, 256, 0, stream>>>(Qb, Kb, Vt, bias, out);
}